// Round 5
// baseline (111.074 us; speedup 1.0000x reference)
//
#include <hip/hip_runtime.h>

// Gaussian 3x3 conv forward, B=64, C=1, H=W=512, N_MULT=1.
// taps = max(rint(clamp(w,0.001,0.999)*clamp(wf,1.001,254.999)), 0.001), then
// 3x3 conv, zero padding=1. Output [1,64,1,512,512] fp32 (flat layout == input).
//
// Full-row wave mapping: one wave64 owns an entire 512-float row; each lane
// holds two float4s (row4[lane], row4[lane+64]). Wave edges == image edges, so
// ALL horizontal halos are shuffles/broadcasts — zero scalar fix-up loads.
// Each thread computes a 4-row tile: per tile 6 rows x 2 coalesced dwordx4
// loads + 8 dwordx4 nontemporal stores (2.5 VMEM wave-ops per KB of output,
// vs 4.75 in the half-row version).

#define BB 64
#define HH 512
#define WW 512
#define RR 4          // output rows per thread

typedef float vfloat4 __attribute__((ext_vector_type(4)));

__global__ __launch_bounds__(256) void gauss3x3_kernel(
    const float* __restrict__ in,     // [B,1,H,W]
    const float* __restrict__ wgt,    // [1,9]
    const float* __restrict__ wfac,   // [1,1]
    float* __restrict__ out)          // [1,B,1,H,W]
{
    // Derive the 9 taps (redundant per thread; scalar broadcast loads).
    float wf = fminf(fmaxf(wfac[0], 1.001f), 254.999f);
    float k[9];
#pragma unroll
    for (int i = 0; i < 9; ++i) {
        float wc = fminf(fmaxf(wgt[i], 0.001f), 0.999f);
        k[i] = fmaxf(rintf(wc * wf), 0.001f);   // rintf = round-half-even = jnp.round
    }

    const int gtid  = blockIdx.x * blockDim.x + threadIdx.x;
    const int lane  = threadIdx.x & 63;
    const int wid   = gtid >> 6;                 // wave id: [0, BB*HH/RR)
    const int strip = wid & (HH / RR - 1);       // wave-uniform: 4-row strip
    const int b     = wid >> 7;                  // wave-uniform: batch (HH/RR=128)
    if (b >= BB) return;

    const int y0 = strip * RR;
    const float* img  = in  + (size_t)b * HH * WW;
    float*       outp = out + (size_t)b * HH * WW;

    float4 acc1[RR], acc2[RR];
#pragma unroll
    for (int i = 0; i < RR; ++i) {
        acc1[i] = make_float4(0.f, 0.f, 0.f, 0.f);
        acc2[i] = make_float4(0.f, 0.f, 0.f, 0.f);
    }

    // Input rows j=0..RR+1 map to ry = y0-1+j. Input row j contributes to
    // output row i=j-t with tap row t (t=0: k[0..2], t=1: k[3..5], t=2: k[6..8]).
#pragma unroll
    for (int j = 0; j < RR + 2; ++j) {
        const int ry = y0 - 1 + j;
        float4 c1 = make_float4(0.f, 0.f, 0.f, 0.f);
        float4 c2 = c1;
        float l1 = 0.f, r1 = 0.f, l2 = 0.f, r2 = 0.f;
        if (ry >= 0 && ry < HH) {                // wave-uniform branch
            const float4* row4 = (const float4*)(img + (size_t)ry * WW);
            c1 = row4[lane];                     // elements [4*lane .. 4*lane+3]
            c2 = row4[lane + 64];                // elements [256+4*lane .. +3]
            // Horizontal halos — all in-register:
            float l1n = __shfl_up(c1.w, 1);      // lane-1's last elem
            float r1n = __shfl_down(c1.x, 1);    // lane+1's first elem
            float l2n = __shfl_up(c2.w, 1);
            float r2n = __shfl_down(c2.x, 1);
            float b0  = __shfl(c2.x, 0);         // element 256 (block 64's first)
            float a63 = __shfl(c1.w, 63);        // element 255 (block 63's last)
            l1 = (lane == 0)  ? 0.f : l1n;       // true left image edge
            r1 = (lane == 63) ? b0  : r1n;       // seam between halves
            l2 = (lane == 0)  ? a63 : l2n;       // seam between halves
            r2 = (lane == 63) ? 0.f : r2n;       // true right image edge
        }
#pragma unroll
        for (int t = 0; t < 3; ++t) {
            const int i = j - t;
            if (i >= 0 && i < RR) {
                const float kl = k[t * 3 + 0];
                const float kc = k[t * 3 + 1];
                const float kr = k[t * 3 + 2];
                acc1[i].x = fmaf(kl, l1,   fmaf(kc, c1.x, fmaf(kr, c1.y, acc1[i].x)));
                acc1[i].y = fmaf(kl, c1.x, fmaf(kc, c1.y, fmaf(kr, c1.z, acc1[i].y)));
                acc1[i].z = fmaf(kl, c1.y, fmaf(kc, c1.z, fmaf(kr, c1.w, acc1[i].z)));
                acc1[i].w = fmaf(kl, c1.z, fmaf(kc, c1.w, fmaf(kr, r1,   acc1[i].w)));
                acc2[i].x = fmaf(kl, l2,   fmaf(kc, c2.x, fmaf(kr, c2.y, acc2[i].x)));
                acc2[i].y = fmaf(kl, c2.x, fmaf(kc, c2.y, fmaf(kr, c2.z, acc2[i].y)));
                acc2[i].z = fmaf(kl, c2.y, fmaf(kc, c2.z, fmaf(kr, c2.w, acc2[i].z)));
                acc2[i].w = fmaf(kl, c2.z, fmaf(kc, c2.w, fmaf(kr, r2,   acc2[i].w)));
            }
        }
    }

#pragma unroll
    for (int i = 0; i < RR; ++i) {
        float* rowo = outp + (size_t)(y0 + i) * WW;
        vfloat4 v1 = { acc1[i].x, acc1[i].y, acc1[i].z, acc1[i].w };
        vfloat4 v2 = { acc2[i].x, acc2[i].y, acc2[i].z, acc2[i].w };
        __builtin_nontemporal_store(v1, (vfloat4*)rowo + lane);
        __builtin_nontemporal_store(v2, (vfloat4*)rowo + lane + 64);
    }
}

extern "C" void kernel_launch(void* const* d_in, const int* in_sizes, int n_in,
                              void* d_out, int out_size, void* d_ws, size_t ws_size,
                              hipStream_t stream) {
    const float* in   = (const float*)d_in[0];   // [64,1,512,512]
    const float* wgt  = (const float*)d_in[1];   // [1,9]
    const float* wfac = (const float*)d_in[2];   // [1,1]
    float* out = (float*)d_out;                  // [1,64,1,512,512]

    const int total = BB * (HH / RR) * 64;       // 524,288 threads (8192 waves)
    const int block = 256;
    const int grid  = total / block;             // 2048
    gauss3x3_kernel<<<grid, block, 0, stream>>>(in, wgt, wfac, out);
}